// Round 12
// baseline (614.992 us; speedup 1.0000x reference)
//
#include <hip/hip_runtime.h>
#include <hip/hip_bf16.h>

#define NB 8
#define NP 8192
#define NC 6
#define NG 512
#define GS 32

#define CENTER_OFF (NB * NG * GS * NC)        /* 786432 */
#define IDX_OFF    (CENTER_OFF + NB * NG * 3) /* 798720 */

// Dtypes (validated R6-R11): d_in[0] f32, d_out f32; _rn math in the
// reference's association order. Selection: fps = (max dist, tie -> min idx);
// knn = (min d2, tie -> min idx) == lax.top_k stable order. u64 keys unique.
// R16 (benched R23): atomic-u64-max combine 561->465 us fps; VALUBusy 2.54%
// of 3.125% ceiling (8/256 CUs) -> ~81% VALU-issue-occupied = ISSUE-BOUND.
// R24 FAILED (absmax 8186 = 8191-5): I maxed/read kslot[it&1] while zeroing
// kslot[(it+2)&3] -> at it%4==2 the zero hits the SAME slot being maxed in
// the same phase (unordered LDS race) -> g=0 -> gi=8191. The 4-slot
// rotation REQUIRES slot = it&3: maxed@it (pre-B_it), read@it (post-B_it),
// zeroed@it+2 (pre-B_{it+2}); every access pair separated by >=1 barrier.
// R25: restore it&3. Keep R24's issue cuts: (1) predicated atomicMax from
// max-holding lanes (sv==smax) -- u64 max over (sv<<32)|lo IS the tie-break
// (max lo = min p), deleting ballot/ctz/while machinery; (2) max3-fusable
// linear fmax chain; (3) hoisted ntid. Keys >= 0 so zero-init never wins.

#define DPP_MAX_U32(v, ctrl)                                               \
  {                                                                        \
    unsigned _m = (unsigned)__builtin_amdgcn_update_dpp(                   \
        (int)(v), (int)(v), (ctrl), 0xf, 0xf, false);                      \
    (v) = (_m > (v)) ? _m : (v);                                           \
  }
#define DPP_MIN_U32(v, ctrl)                                               \
  {                                                                        \
    unsigned _m = (unsigned)__builtin_amdgcn_update_dpp(                   \
        (int)(v), (int)(v), (ctrl), 0xf, 0xf, false);                      \
    (v) = (_m < (v)) ? _m : (v);                                           \
  }

// ---------------------------------------------------------------------------
// Kernel 1: FPS. 1024 thr (16 waves), 8 pts/thread. max3 chain + first-j
// scan (8-deep); DPP max + readlane broadcast; predicated ds_max_u64 into
// kslot[it&3] from max-holding lanes + single broadcast read. ONE
// barrier/iter; float4 LDS mirror for winner gather; epilogue writes.
// ---------------------------------------------------------------------------
__global__ __launch_bounds__(1024) void fps_kernel(
    const float* __restrict__ xyz, float* __restrict__ out,
    int* __restrict__ cidx)
{
  __shared__ float4 mir[NP];                    // 128 KB point mirror
  __shared__ unsigned long long kslot[4];       // rotating combine slots
  __shared__ int sel[NG];

  const int b = blockIdx.x;
  const int tid = threadIdx.x;
  const float* base = xyz + (size_t)b * NP * NC;
  const unsigned ntid = (unsigned)(NP - 1 - tid);

  float px[8], py[8], pz[8], dv[8];
#pragma unroll
  for (int j = 0; j < 8; ++j) {
    const int p = tid + (j << 10);
    const float2 xy = *reinterpret_cast<const float2*>(base + p * 6);
    px[j] = xy.x;
    py[j] = xy.y;
    pz[j] = base[p * 6 + 2];
    mir[p] = make_float4(px[j], py[j], pz[j], 0.0f);
  }
  if (tid < 4) kslot[tid] = 0ull;
  if (tid == 0) sel[0] = 0;
  __syncthreads();

  float4 c0 = mir[0];
  float cx = c0.x, cy = c0.y, cz = c0.z;

#pragma unroll
  for (int j = 0; j < 8; ++j) {
    const float dx = __fsub_rn(px[j], cx);
    const float dy = __fsub_rn(py[j], cy);
    const float dz = __fsub_rn(pz[j], cz);
    dv[j] = __fadd_rn(
        __fadd_rn(__fmul_rn(dx, dx), __fmul_rn(dy, dy)), __fmul_rn(dz, dz));
  }

  for (int it = 1; it < NG; ++it) {
    // max of 8 (linear chain -> v_max3 fusion; all non-NaN, bit-exact set max)
    float m = fmaxf(dv[0], dv[1]);
    m = fmaxf(m, dv[2]); m = fmaxf(m, dv[3]);
    m = fmaxf(m, dv[4]); m = fmaxf(m, dv[5]);
    m = fmaxf(m, dv[6]); m = fmaxf(m, dv[7]);
    // first j with dv[j]==m (descending loop -> smallest j wins = min p)
    int jj = 0;
#pragma unroll
    for (int j = 7; j >= 0; --j)
      if (dv[j] == m) jj = j;
    const unsigned lo = ntid - (unsigned)(jj << 10);  // 8191 - p

    // wave max of m's bits (dv>=0: u32 order == f32 order)
    const unsigned sv = __float_as_uint(m);
    unsigned r = sv;
    DPP_MAX_U32(r, 0x111); DPP_MAX_U32(r, 0x112); DPP_MAX_U32(r, 0x114);
    DPP_MAX_U32(r, 0x118); DPP_MAX_U32(r, 0x142); DPP_MAX_U32(r, 0x143);
    const unsigned smax = (unsigned)__builtin_amdgcn_readlane((int)r, 63);

    // Predicated combine: the max-holding lane(s) of each wave issue the
    // u64 atomic max directly into slot it&3 (4-slot rotation: maxed@it,
    // read@it post-B, zeroed@it+2 -- all pairs barrier-separated). Value
    // tie: atomic max over (sv<<32)|lo picks max lo = min p, exact.
    const int sl = it & 3;
    if (sv == smax)
      atomicMax(&kslot[sl],
                ((unsigned long long)sv << 32) | lo);
    if (tid == 0) kslot[(it + 2) & 3] = 0ull;   // prep slot for iter it+2
    __syncthreads();

    // post-barrier chain: ONE broadcast b64 read -> gi -> ONE b128 read.
    const unsigned long long g = kslot[sl];
    const int gi = (NP - 1) - (int)(unsigned)(g & 0xFFFFFFFFu);
    if (tid == 0) sel[it] = gi;

    const float4 c = mir[gi];     // one ds_read_b128 broadcast
    cx = c.x; cy = c.y; cz = c.z;

#pragma unroll
    for (int j = 0; j < 8; ++j) {
      const float dx = __fsub_rn(px[j], cx);
      const float dy = __fsub_rn(py[j], cy);
      const float dz = __fsub_rn(pz[j], cz);
      const float d = __fadd_rn(
          __fadd_rn(__fmul_rn(dx, dx), __fmul_rn(dy, dy)), __fmul_rn(dz, dz));
      dv[j] = fminf(dv[j], d);
    }
  }
  __syncthreads();

  if (tid < NG) {
    const int g = tid;
    const int p = sel[g];
    const float4 c = mir[p];
    const size_t cb = (size_t)(b * NG + g) * 3;
    out[CENTER_OFF + cb + 0] = c.x;
    out[CENTER_OFF + cb + 1] = c.y;
    out[CENTER_OFF + cb + 2] = c.z;
    cidx[b * NG + g] = p;
  }
}

// ---------------------------------------------------------------------------
// Kernel 2: 32-NN, R12: TWO-LEVEL histogram select + tiny-pool extraction.
// L1: 2048 bins of fv>>21 -> bin B1 + run1 (count below).
// L2: re-histogram bin-B1 keys on (fv>>10)&0x7FF -> B2 + run2.
// Winners (< B1, or ==B1 with mid<B2): run1+run2 <= 31. Candidates
// ((fv>>10)==(B1<<11|B2)): ~1-8 expected (2^-13-octave slice), cap 224.
// Wave 0 extracts the 32 smallest u64 keys (DPP+ballot, R10-validated).
// ---------------------------------------------------------------------------
__global__ __launch_bounds__(256) void knn_kernel(
    const float* __restrict__ xyz, float* __restrict__ out,
    const int* __restrict__ cidx)
{
  __shared__ unsigned bins[2048];
  __shared__ unsigned part[256];
  __shared__ int sB, sRun;
  __shared__ unsigned wcnt, ccnt;
  __shared__ unsigned long long wbuf[32];
  __shared__ unsigned long long cbuf[224];
  __shared__ int widx[GS];

  const int bg = blockIdx.x;
  const int b = bg >> 9;
  const int tid = threadIdx.x;
  const int lane = tid & 63;
  const int wave = tid >> 6;
  const float* base = xyz + (size_t)b * NP * NC;

  const int pc = cidx[bg] & (NP - 1);  // clamp: fault-proof under any state
  const float cx = base[pc * 6 + 0];
  const float cy = base[pc * 6 + 1];
  const float cz = base[pc * 6 + 2];
  const float cc = __fadd_rn(
      __fadd_rn(__fmul_rn(cx, cx), __fmul_rn(cy, cy)), __fmul_rn(cz, cz));

  for (int i = tid; i < 2048; i += 256) bins[i] = 0;
  if (tid == 0) { wcnt = 0; ccnt = 0; }
  __syncthreads();

  unsigned fv[32];
#pragma unroll
  for (int j = 0; j < 32; ++j) {
    const int p = tid + (j << 8);
    const float x = base[p * 6 + 0];
    const float y = base[p * 6 + 1];
    const float z = base[p * 6 + 2];
    const float xx = __fadd_rn(
        __fadd_rn(__fmul_rn(x, x), __fmul_rn(y, y)), __fmul_rn(z, z));
    const float dot = __fadd_rn(
        __fadd_rn(__fmul_rn(cx, x), __fmul_rn(cy, y)), __fmul_rn(cz, z));
    const float d2 = __fsub_rn(__fadd_rn(cc, xx), __fmul_rn(2.0f, dot));
    unsigned u = __float_as_uint(d2);
    u ^= ((unsigned)((int)u >> 31)) | 0x80000000u;  // sortable (d2 can be <0)
    fv[j] = u;
    atomicAdd(&bins[u >> 21], 1u);
  }
  __syncthreads();

  // ---- Level 1: bin containing rank 32 ----
  {
    unsigned s = 0;
#pragma unroll
    for (int i = 0; i < 8; ++i) s += bins[tid * 8 + i];
    part[tid] = s;
  }
  __syncthreads();
  if (wave == 0) {
    const unsigned q = part[4 * lane + 0] + part[4 * lane + 1] +
                       part[4 * lane + 2] + part[4 * lane + 3];
    unsigned cum = q;
#pragma unroll
    for (int off = 1; off < 64; off <<= 1) {
      const unsigned t = __shfl_up(cum, (unsigned)off);
      if (lane >= off) cum += t;
    }
    const unsigned long long mb = __ballot(cum >= 32u);
    const int ls = __builtin_ctzll(mb);
    unsigned run = (unsigned)__builtin_amdgcn_readlane((int)cum, ls) -
                   (unsigned)__builtin_amdgcn_readlane((int)q, ls);
    unsigned h[32];
#pragma unroll
    for (int i = 0; i < 32; ++i) h[i] = bins[(ls << 5) + i];  // broadcast
    int T = ls << 5;
#pragma unroll
    for (int i = 0; i < 32; ++i) {
      if (run + h[i] >= 32u) { T = (ls << 5) + i; break; }
      run += h[i];
    }
    if (lane == 0) { sB = T; sRun = (int)run; }
  }
  __syncthreads();
  const int B1 = sB;
  const unsigned run1 = (unsigned)sRun;
  const unsigned r2 = 32u - run1;              // rank within bin B1, in [1,32]
  __syncthreads();

  // ---- Level 2: refine within bin B1 on bits 20..10 ----
  for (int i = tid; i < 2048; i += 256) bins[i] = 0;
  __syncthreads();
#pragma unroll
  for (int j = 0; j < 32; ++j)
    if ((int)(fv[j] >> 21) == B1) atomicAdd(&bins[(fv[j] >> 10) & 0x7FF], 1u);
  __syncthreads();
  {
    unsigned s = 0;
#pragma unroll
    for (int i = 0; i < 8; ++i) s += bins[tid * 8 + i];
    part[tid] = s;
  }
  __syncthreads();
  if (wave == 0) {
    const unsigned q = part[4 * lane + 0] + part[4 * lane + 1] +
                       part[4 * lane + 2] + part[4 * lane + 3];
    unsigned cum = q;
#pragma unroll
    for (int off = 1; off < 64; off <<= 1) {
      const unsigned t = __shfl_up(cum, (unsigned)off);
      if (lane >= off) cum += t;
    }
    const unsigned long long mb = __ballot(cum >= r2);  // total >= r2 always
    const int ls = __builtin_ctzll(mb);
    unsigned run = (unsigned)__builtin_amdgcn_readlane((int)cum, ls) -
                   (unsigned)__builtin_amdgcn_readlane((int)q, ls);
    unsigned h[32];
#pragma unroll
    for (int i = 0; i < 32; ++i) h[i] = bins[(ls << 5) + i];
    int T = ls << 5;
#pragma unroll
    for (int i = 0; i < 32; ++i) {
      if (run + h[i] >= r2) { T = (ls << 5) + i; break; }
      run += h[i];
    }
    if (lane == 0) { sB = T; sRun = (int)run; }
  }
  __syncthreads();
  const int B2 = sB;                            // run1 + sRun <= 31 winners
  const unsigned key22 = ((unsigned)B1 << 11) | (unsigned)B2;

  // ---- compaction ----
#pragma unroll
  for (int j = 0; j < 32; ++j) {
    const unsigned hi11 = fv[j] >> 21;
    const unsigned top22 = fv[j] >> 10;
    if (top22 <= key22) {
      const unsigned long long key =
          ((unsigned long long)fv[j] << 32) | (unsigned)(tid + (j << 8));
      if (top22 < key22) {
        if ((int)hi11 < B1 || hi11 == (unsigned)B1) {  // always true; winners
          const unsigned pos = atomicAdd(&wcnt, 1u);
          if (pos < 32u) wbuf[pos] = key;
        }
      } else {
        const unsigned pos = atomicAdd(&ccnt, 1u);
        if (pos < 224u) cbuf[pos] = key;
      }
    }
  }
  __syncthreads();

  // ---- wave 0: extract 32 smallest u64 keys from the pool ----
  if (wave == 0) {
    const int W = (int)(wcnt < 32u ? wcnt : 32u);     // provably <= 31
    const int C = (int)(ccnt < 224u ? ccnt : 224u);
    unsigned long long pool[4];
#pragma unroll
    for (int rr = 0; rr < 4; ++rr) {
      const int i = lane + (rr << 6);
      unsigned long long k = ~0ull;
      if (i < W) k = wbuf[i];
      else if (i - W < C) k = cbuf[i - W];
      pool[rr] = k;
    }
    unsigned long long l0 = pool[0] < pool[1] ? pool[0] : pool[1];
    unsigned long long l1 = pool[2] < pool[3] ? pool[2] : pool[3];
    unsigned long long loc = l0 < l1 ? l0 : l1;

    unsigned long long mykey = 0;
    for (int k = 0; k < GS; ++k) {
      const unsigned hi = (unsigned)(loc >> 32);
      unsigned r = hi;
      DPP_MIN_U32(r, 0x111); DPP_MIN_U32(r, 0x112); DPP_MIN_U32(r, 0x114);
      DPP_MIN_U32(r, 0x118); DPP_MIN_U32(r, 0x142); DPP_MIN_U32(r, 0x143);
      const unsigned minhi = (unsigned)__builtin_amdgcn_readlane((int)r, 63);

      const unsigned long long m = __ballot(hi == minhi);
      unsigned lo;
      if (m & (m - 1)) {                       // value tie: min low word
        unsigned long long mm = m; unsigned best = 0xFFFFFFFFu;
        while (mm) {
          const int l = __builtin_ctzll(mm);
          const unsigned c =
              (unsigned)__builtin_amdgcn_readlane((int)(unsigned)loc, l);
          if (c < best) best = c;
          mm &= mm - 1;
        }
        lo = best;
      } else {
        lo = (unsigned)__builtin_amdgcn_readlane((int)(unsigned)loc,
                                                 __builtin_ctzll(m));
      }
      const unsigned long long win = ((unsigned long long)minhi << 32) | lo;
      if (lane == k) mykey = win;
      if (loc == win) {                        // unique owner (keys unique)
#pragma unroll
        for (int rr = 0; rr < 4; ++rr)
          if (pool[rr] == win) pool[rr] = ~0ull;
        l0 = pool[0] < pool[1] ? pool[0] : pool[1];
        l1 = pool[2] < pool[3] ? pool[2] : pool[3];
        loc = l0 < l1 ? l0 : l1;
      }
    }
    if (lane < GS) widx[lane] = (int)(unsigned)(mykey & 0xFFFFFFFFu);
  }
  __syncthreads();

  if (tid < GS) {
    const int p = widx[tid] & (NP - 1);  // in-bounds by construction
    const float v0 = base[p * 6 + 0];
    const float v1 = base[p * 6 + 1];
    const float v2 = base[p * 6 + 2];
    const size_t ob = ((size_t)bg * GS + tid) * 6;
    out[ob + 0] = __fsub_rn(v0, cx);
    out[ob + 1] = __fsub_rn(v1, cy);
    out[ob + 2] = __fsub_rn(v2, cz);
    out[ob + 3] = base[p * 6 + 3];  // extras: raw f32 passthrough
    out[ob + 4] = base[p * 6 + 4];
    out[ob + 5] = base[p * 6 + 5];
    out[IDX_OFF + (size_t)bg * GS + tid] = (float)p;  // idx as f32 value
  }
}

extern "C" void kernel_launch(void* const* d_in, const int* in_sizes, int n_in,
                              void* d_out, int out_size, void* d_ws,
                              size_t ws_size, hipStream_t stream)
{
  const float* xyz = (const float*)d_in[0];
  float* out = (float*)d_out;
  int* cidx = (int*)d_ws;  // NB*NG ints = 16 KiB scratch

  hipLaunchKernelGGL(fps_kernel, dim3(NB), dim3(1024), 0, stream,
                     xyz, out, cidx);
  hipLaunchKernelGGL(knn_kernel, dim3(NB * NG), dim3(256), 0, stream,
                     xyz, out, cidx);
}

// Round 13
// 614.752 us; speedup vs baseline: 1.0004x; 1.0004x over previous
//
#include <hip/hip_runtime.h>
#include <hip/hip_bf16.h>

#define NB 8
#define NP 8192
#define NC 6
#define NG 512
#define GS 32

#define CENTER_OFF (NB * NG * GS * NC)        /* 786432 */
#define IDX_OFF    (CENTER_OFF + NB * NG * 3) /* 798720 */

// Dtypes (validated R6-R11): d_in[0] f32, d_out f32; _rn math in the
// reference's association order. Selection: fps = (max dist, tie -> min idx);
// knn = (min d2, tie -> min idx) == lax.top_k stable order. u64 keys unique.
// R16 (benched R23): atomic-u64-max combine, 465 us fps, 2184 cyc/iter;
// VALUBusy 2.54% of 3.125% ceiling -> ~81% VALU-issue-occupied.
// R25 post-mortem: bundled {predicated atomic + tree->linear fmax chain}
// REGRESSED to 481 us (+75 cyc/iter), VALUBusy ~same -> exposed-latency
// growth, not issue growth. Linear chain depth 7 vs tree depth 3 feeds the
// scan->DPP->atomic->barrier path (only ~19% stall headroom, R23) ->
// regression attributed to the chain. Predicated atomic itself should be
// neutral-to-positive (deletes ballot/ctz/readlane; multi-lane atomic only
// on exact f32 ties, rare).
// R26: UNBUNDLE -- restore R16's tree max exactly; keep ONLY the
// predicated atomicMax resolve as the single delta vs the 465-us kernel.
// u64 max over (sv<<32)|lo IS the tie-break (max lo = min p), bit-exact.
// 4-slot kslot rotation (slot = it&3) per R16 proof; keys >= 0.

#define DPP_MAX_U32(v, ctrl)                                               \
  {                                                                        \
    unsigned _m = (unsigned)__builtin_amdgcn_update_dpp(                   \
        (int)(v), (int)(v), (ctrl), 0xf, 0xf, false);                      \
    (v) = (_m > (v)) ? _m : (v);                                           \
  }
#define DPP_MIN_U32(v, ctrl)                                               \
  {                                                                        \
    unsigned _m = (unsigned)__builtin_amdgcn_update_dpp(                   \
        (int)(v), (int)(v), (ctrl), 0xf, 0xf, false);                      \
    (v) = (_m < (v)) ? _m : (v);                                           \
  }

// ---------------------------------------------------------------------------
// Kernel 1: FPS. 1024 thr (16 waves), 8 pts/thread. f32 max TREE (depth 3,
// R16-validated) + first-j scan (8-deep); DPP max + readlane broadcast;
// predicated ds_max_u64 into kslot[it&3] from max-holding lanes + single
// broadcast read. ONE barrier/iter; float4 LDS mirror; epilogue writes.
// ---------------------------------------------------------------------------
__global__ __launch_bounds__(1024) void fps_kernel(
    const float* __restrict__ xyz, float* __restrict__ out,
    int* __restrict__ cidx)
{
  __shared__ float4 mir[NP];                    // 128 KB point mirror
  __shared__ unsigned long long kslot[4];       // rotating combine slots
  __shared__ int sel[NG];

  const int b = blockIdx.x;
  const int tid = threadIdx.x;
  const float* base = xyz + (size_t)b * NP * NC;

  float px[8], py[8], pz[8], dv[8];
#pragma unroll
  for (int j = 0; j < 8; ++j) {
    const int p = tid + (j << 10);
    const float2 xy = *reinterpret_cast<const float2*>(base + p * 6);
    px[j] = xy.x;
    py[j] = xy.y;
    pz[j] = base[p * 6 + 2];
    mir[p] = make_float4(px[j], py[j], pz[j], 0.0f);
  }
  if (tid < 4) kslot[tid] = 0ull;
  if (tid == 0) sel[0] = 0;
  __syncthreads();

  float4 c0 = mir[0];
  float cx = c0.x, cy = c0.y, cz = c0.z;

#pragma unroll
  for (int j = 0; j < 8; ++j) {
    const float dx = __fsub_rn(px[j], cx);
    const float dy = __fsub_rn(py[j], cy);
    const float dz = __fsub_rn(pz[j], cz);
    dv[j] = __fadd_rn(
        __fadd_rn(__fmul_rn(dx, dx), __fmul_rn(dy, dy)), __fmul_rn(dz, dz));
  }

  for (int it = 1; it < NG; ++it) {
    // f32 max tree, depth 3 (fmax returns an input bit-exactly; no NaN)
    float t[4];
#pragma unroll
    for (int j = 0; j < 4; ++j) t[j] = fmaxf(dv[j], dv[j + 4]);
    t[0] = fmaxf(t[0], t[2]);
    t[1] = fmaxf(t[1], t[3]);
    const float m = fmaxf(t[0], t[1]);
    // first j with dv[j]==m (descending loop -> smallest j wins = min p)
    int jj = 0;
#pragma unroll
    for (int j = 7; j >= 0; --j)
      if (dv[j] == m) jj = j;
    const unsigned lo = (unsigned)(NP - 1 - tid - (jj << 10));  // 8191 - p

    // wave max of m's bits (dv>=0: u32 order == f32 order)
    const unsigned sv = __float_as_uint(m);
    unsigned r = sv;
    DPP_MAX_U32(r, 0x111); DPP_MAX_U32(r, 0x112); DPP_MAX_U32(r, 0x114);
    DPP_MAX_U32(r, 0x118); DPP_MAX_U32(r, 0x142); DPP_MAX_U32(r, 0x143);
    const unsigned smax = (unsigned)__builtin_amdgcn_readlane((int)r, 63);

    // Predicated combine: the max-holding lane(s) of each wave issue the
    // u64 atomic max directly into slot it&3 (4-slot rotation: maxed@it,
    // read@it post-B, zeroed@it+2 -- all pairs barrier-separated). Value
    // tie: atomic max over (sv<<32)|lo picks max lo = min p, exact.
    const int sl = it & 3;
    if (sv == smax)
      atomicMax(&kslot[sl],
                ((unsigned long long)sv << 32) | lo);
    if (tid == 0) kslot[(it + 2) & 3] = 0ull;   // prep slot for iter it+2
    __syncthreads();

    // post-barrier chain: ONE broadcast b64 read -> gi -> ONE b128 read.
    const unsigned long long g = kslot[sl];
    const int gi = (NP - 1) - (int)(unsigned)(g & 0xFFFFFFFFu);
    if (tid == 0) sel[it] = gi;

    const float4 c = mir[gi];     // one ds_read_b128 broadcast
    cx = c.x; cy = c.y; cz = c.z;

#pragma unroll
    for (int j = 0; j < 8; ++j) {
      const float dx = __fsub_rn(px[j], cx);
      const float dy = __fsub_rn(py[j], cy);
      const float dz = __fsub_rn(pz[j], cz);
      const float d = __fadd_rn(
          __fadd_rn(__fmul_rn(dx, dx), __fmul_rn(dy, dy)), __fmul_rn(dz, dz));
      dv[j] = fminf(dv[j], d);
    }
  }
  __syncthreads();

  if (tid < NG) {
    const int g = tid;
    const int p = sel[g];
    const float4 c = mir[p];
    const size_t cb = (size_t)(b * NG + g) * 3;
    out[CENTER_OFF + cb + 0] = c.x;
    out[CENTER_OFF + cb + 1] = c.y;
    out[CENTER_OFF + cb + 2] = c.z;
    cidx[b * NG + g] = p;
  }
}

// ---------------------------------------------------------------------------
// Kernel 2: 32-NN, R12: TWO-LEVEL histogram select + tiny-pool extraction.
// L1: 2048 bins of fv>>21 -> bin B1 + run1 (count below).
// L2: re-histogram bin-B1 keys on (fv>>10)&0x7FF -> B2 + run2.
// Winners (< B1, or ==B1 with mid<B2): run1+run2 <= 31. Candidates
// ((fv>>10)==(B1<<11|B2)): ~1-8 expected (2^-13-octave slice), cap 224.
// Wave 0 extracts the 32 smallest u64 keys (DPP+ballot, R10-validated).
// ---------------------------------------------------------------------------
__global__ __launch_bounds__(256) void knn_kernel(
    const float* __restrict__ xyz, float* __restrict__ out,
    const int* __restrict__ cidx)
{
  __shared__ unsigned bins[2048];
  __shared__ unsigned part[256];
  __shared__ int sB, sRun;
  __shared__ unsigned wcnt, ccnt;
  __shared__ unsigned long long wbuf[32];
  __shared__ unsigned long long cbuf[224];
  __shared__ int widx[GS];

  const int bg = blockIdx.x;
  const int b = bg >> 9;
  const int tid = threadIdx.x;
  const int lane = tid & 63;
  const int wave = tid >> 6;
  const float* base = xyz + (size_t)b * NP * NC;

  const int pc = cidx[bg] & (NP - 1);  // clamp: fault-proof under any state
  const float cx = base[pc * 6 + 0];
  const float cy = base[pc * 6 + 1];
  const float cz = base[pc * 6 + 2];
  const float cc = __fadd_rn(
      __fadd_rn(__fmul_rn(cx, cx), __fmul_rn(cy, cy)), __fmul_rn(cz, cz));

  for (int i = tid; i < 2048; i += 256) bins[i] = 0;
  if (tid == 0) { wcnt = 0; ccnt = 0; }
  __syncthreads();

  unsigned fv[32];
#pragma unroll
  for (int j = 0; j < 32; ++j) {
    const int p = tid + (j << 8);
    const float x = base[p * 6 + 0];
    const float y = base[p * 6 + 1];
    const float z = base[p * 6 + 2];
    const float xx = __fadd_rn(
        __fadd_rn(__fmul_rn(x, x), __fmul_rn(y, y)), __fmul_rn(z, z));
    const float dot = __fadd_rn(
        __fadd_rn(__fmul_rn(cx, x), __fmul_rn(cy, y)), __fmul_rn(cz, z));
    const float d2 = __fsub_rn(__fadd_rn(cc, xx), __fmul_rn(2.0f, dot));
    unsigned u = __float_as_uint(d2);
    u ^= ((unsigned)((int)u >> 31)) | 0x80000000u;  // sortable (d2 can be <0)
    fv[j] = u;
    atomicAdd(&bins[u >> 21], 1u);
  }
  __syncthreads();

  // ---- Level 1: bin containing rank 32 ----
  {
    unsigned s = 0;
#pragma unroll
    for (int i = 0; i < 8; ++i) s += bins[tid * 8 + i];
    part[tid] = s;
  }
  __syncthreads();
  if (wave == 0) {
    const unsigned q = part[4 * lane + 0] + part[4 * lane + 1] +
                       part[4 * lane + 2] + part[4 * lane + 3];
    unsigned cum = q;
#pragma unroll
    for (int off = 1; off < 64; off <<= 1) {
      const unsigned t = __shfl_up(cum, (unsigned)off);
      if (lane >= off) cum += t;
    }
    const unsigned long long mb = __ballot(cum >= 32u);
    const int ls = __builtin_ctzll(mb);
    unsigned run = (unsigned)__builtin_amdgcn_readlane((int)cum, ls) -
                   (unsigned)__builtin_amdgcn_readlane((int)q, ls);
    unsigned h[32];
#pragma unroll
    for (int i = 0; i < 32; ++i) h[i] = bins[(ls << 5) + i];  // broadcast
    int T = ls << 5;
#pragma unroll
    for (int i = 0; i < 32; ++i) {
      if (run + h[i] >= 32u) { T = (ls << 5) + i; break; }
      run += h[i];
    }
    if (lane == 0) { sB = T; sRun = (int)run; }
  }
  __syncthreads();
  const int B1 = sB;
  const unsigned run1 = (unsigned)sRun;
  const unsigned r2 = 32u - run1;              // rank within bin B1, in [1,32]
  __syncthreads();

  // ---- Level 2: refine within bin B1 on bits 20..10 ----
  for (int i = tid; i < 2048; i += 256) bins[i] = 0;
  __syncthreads();
#pragma unroll
  for (int j = 0; j < 32; ++j)
    if ((int)(fv[j] >> 21) == B1) atomicAdd(&bins[(fv[j] >> 10) & 0x7FF], 1u);
  __syncthreads();
  {
    unsigned s = 0;
#pragma unroll
    for (int i = 0; i < 8; ++i) s += bins[tid * 8 + i];
    part[tid] = s;
  }
  __syncthreads();
  if (wave == 0) {
    const unsigned q = part[4 * lane + 0] + part[4 * lane + 1] +
                       part[4 * lane + 2] + part[4 * lane + 3];
    unsigned cum = q;
#pragma unroll
    for (int off = 1; off < 64; off <<= 1) {
      const unsigned t = __shfl_up(cum, (unsigned)off);
      if (lane >= off) cum += t;
    }
    const unsigned long long mb = __ballot(cum >= r2);  // total >= r2 always
    const int ls = __builtin_ctzll(mb);
    unsigned run = (unsigned)__builtin_amdgcn_readlane((int)cum, ls) -
                   (unsigned)__builtin_amdgcn_readlane((int)q, ls);
    unsigned h[32];
#pragma unroll
    for (int i = 0; i < 32; ++i) h[i] = bins[(ls << 5) + i];
    int T = ls << 5;
#pragma unroll
    for (int i = 0; i < 32; ++i) {
      if (run + h[i] >= r2) { T = (ls << 5) + i; break; }
      run += h[i];
    }
    if (lane == 0) { sB = T; sRun = (int)run; }
  }
  __syncthreads();
  const int B2 = sB;                            // run1 + sRun <= 31 winners
  const unsigned key22 = ((unsigned)B1 << 11) | (unsigned)B2;

  // ---- compaction ----
#pragma unroll
  for (int j = 0; j < 32; ++j) {
    const unsigned hi11 = fv[j] >> 21;
    const unsigned top22 = fv[j] >> 10;
    if (top22 <= key22) {
      const unsigned long long key =
          ((unsigned long long)fv[j] << 32) | (unsigned)(tid + (j << 8));
      if (top22 < key22) {
        if ((int)hi11 < B1 || hi11 == (unsigned)B1) {  // always true; winners
          const unsigned pos = atomicAdd(&wcnt, 1u);
          if (pos < 32u) wbuf[pos] = key;
        }
      } else {
        const unsigned pos = atomicAdd(&ccnt, 1u);
        if (pos < 224u) cbuf[pos] = key;
      }
    }
  }
  __syncthreads();

  // ---- wave 0: extract 32 smallest u64 keys from the pool ----
  if (wave == 0) {
    const int W = (int)(wcnt < 32u ? wcnt : 32u);     // provably <= 31
    const int C = (int)(ccnt < 224u ? ccnt : 224u);
    unsigned long long pool[4];
#pragma unroll
    for (int rr = 0; rr < 4; ++rr) {
      const int i = lane + (rr << 6);
      unsigned long long k = ~0ull;
      if (i < W) k = wbuf[i];
      else if (i - W < C) k = cbuf[i - W];
      pool[rr] = k;
    }
    unsigned long long l0 = pool[0] < pool[1] ? pool[0] : pool[1];
    unsigned long long l1 = pool[2] < pool[3] ? pool[2] : pool[3];
    unsigned long long loc = l0 < l1 ? l0 : l1;

    unsigned long long mykey = 0;
    for (int k = 0; k < GS; ++k) {
      const unsigned hi = (unsigned)(loc >> 32);
      unsigned r = hi;
      DPP_MIN_U32(r, 0x111); DPP_MIN_U32(r, 0x112); DPP_MIN_U32(r, 0x114);
      DPP_MIN_U32(r, 0x118); DPP_MIN_U32(r, 0x142); DPP_MIN_U32(r, 0x143);
      const unsigned minhi = (unsigned)__builtin_amdgcn_readlane((int)r, 63);

      const unsigned long long m = __ballot(hi == minhi);
      unsigned lo;
      if (m & (m - 1)) {                       // value tie: min low word
        unsigned long long mm = m; unsigned best = 0xFFFFFFFFu;
        while (mm) {
          const int l = __builtin_ctzll(mm);
          const unsigned c =
              (unsigned)__builtin_amdgcn_readlane((int)(unsigned)loc, l);
          if (c < best) best = c;
          mm &= mm - 1;
        }
        lo = best;
      } else {
        lo = (unsigned)__builtin_amdgcn_readlane((int)(unsigned)loc,
                                                 __builtin_ctzll(m));
      }
      const unsigned long long win = ((unsigned long long)minhi << 32) | lo;
      if (lane == k) mykey = win;
      if (loc == win) {                        // unique owner (keys unique)
#pragma unroll
        for (int rr = 0; rr < 4; ++rr)
          if (pool[rr] == win) pool[rr] = ~0ull;
        l0 = pool[0] < pool[1] ? pool[0] : pool[1];
        l1 = pool[2] < pool[3] ? pool[2] : pool[3];
        loc = l0 < l1 ? l0 : l1;
      }
    }
    if (lane < GS) widx[lane] = (int)(unsigned)(mykey & 0xFFFFFFFFu);
  }
  __syncthreads();

  if (tid < GS) {
    const int p = widx[tid] & (NP - 1);  // in-bounds by construction
    const float v0 = base[p * 6 + 0];
    const float v1 = base[p * 6 + 1];
    const float v2 = base[p * 6 + 2];
    const size_t ob = ((size_t)bg * GS + tid) * 6;
    out[ob + 0] = __fsub_rn(v0, cx);
    out[ob + 1] = __fsub_rn(v1, cy);
    out[ob + 2] = __fsub_rn(v2, cz);
    out[ob + 3] = base[p * 6 + 3];  // extras: raw f32 passthrough
    out[ob + 4] = base[p * 6 + 4];
    out[ob + 5] = base[p * 6 + 5];
    out[IDX_OFF + (size_t)bg * GS + tid] = (float)p;  // idx as f32 value
  }
}

extern "C" void kernel_launch(void* const* d_in, const int* in_sizes, int n_in,
                              void* d_out, int out_size, void* d_ws,
                              size_t ws_size, hipStream_t stream)
{
  const float* xyz = (const float*)d_in[0];
  float* out = (float*)d_out;
  int* cidx = (int*)d_ws;  // NB*NG ints = 16 KiB scratch

  hipLaunchKernelGGL(fps_kernel, dim3(NB), dim3(1024), 0, stream,
                     xyz, out, cidx);
  hipLaunchKernelGGL(knn_kernel, dim3(NB * NG), dim3(256), 0, stream,
                     xyz, out, cidx);
}

// Round 14
// 586.687 us; speedup vs baseline: 1.0482x; 1.0478x over previous
//
#include <hip/hip_runtime.h>
#include <hip/hip_bf16.h>

#define NB 8
#define NP 8192
#define NC 6
#define NG 512
#define GS 32

#define CENTER_OFF (NB * NG * GS * NC)        /* 786432 */
#define IDX_OFF    (CENTER_OFF + NB * NG * 3) /* 798720 */

// Dtypes (validated R6-R11): d_in[0] f32, d_out f32; _rn math in the
// reference's association order. Selection: fps = (max dist, tie -> min idx);
// knn = (min d2, tie -> min idx) == lax.top_k stable order. u64 keys unique.
// fps history: R16 (465 us, benched 2x) = tree max + ballot resolve +
// lane0 atomic-u64-max into kslot[it&3] (4-slot rotation, barrier-proof).
// R25 (481) and R26 (486) both carried a PREDICATED atomicMax (sv==smax)
// -> unbundle attributes the ~+100 cyc/iter regression to it: per-lane
// VALU u64 key build under data-dependent exec mask on the DPP critical
// path, vs R16's SALU key from readlane + static lane==0 branch. VALUBusy
// unchanged -> exposed latency, not issue. R27: fps reverted to EXACT R16.
// fps is issue-bound (VALUBusy 2.54% of 3.125% 8-CU ceiling = 81%);
// further source-level cuts regressed twice -> parked.
// R27 knn delta: vectorize point loads (float2 xy + scalar z, 24B stride
// -> 8B aligned, same pattern as fps staging). Bit-exact values; cuts
// per-thread loads 96->64. knn timed separately -> clean attribution.

#define DPP_MAX_U32(v, ctrl)                                               \
  {                                                                        \
    unsigned _m = (unsigned)__builtin_amdgcn_update_dpp(                   \
        (int)(v), (int)(v), (ctrl), 0xf, 0xf, false);                      \
    (v) = (_m > (v)) ? _m : (v);                                           \
  }
#define DPP_MIN_U32(v, ctrl)                                               \
  {                                                                        \
    unsigned _m = (unsigned)__builtin_amdgcn_update_dpp(                   \
        (int)(v), (int)(v), (ctrl), 0xf, 0xf, false);                      \
    (v) = (_m < (v)) ? _m : (v);                                           \
  }

// ---------------------------------------------------------------------------
// Kernel 1: FPS. EXACT R16 (benched 465 us). 1024 thr (16 waves), 8
// pts/thread. f32 max tree (depth 3) + first-j scan; DPP max + ballot
// arg-resolve; lane0 ds_max_u64 into kslot[it&3] + single broadcast read.
// ONE barrier/iter; float4 LDS mirror for winner gather; epilogue writes.
// ---------------------------------------------------------------------------
__global__ __launch_bounds__(1024) void fps_kernel(
    const float* __restrict__ xyz, float* __restrict__ out,
    int* __restrict__ cidx)
{
  __shared__ float4 mir[NP];                    // 128 KB point mirror
  __shared__ unsigned long long kslot[4];       // rotating combine slots
  __shared__ int sel[NG];

  const int b = blockIdx.x;
  const int tid = threadIdx.x;
  const int lane = tid & 63;
  const float* base = xyz + (size_t)b * NP * NC;

  float px[8], py[8], pz[8], dv[8];
#pragma unroll
  for (int j = 0; j < 8; ++j) {
    const int p = tid + (j << 10);
    const float2 xy = *reinterpret_cast<const float2*>(base + p * 6);
    px[j] = xy.x;
    py[j] = xy.y;
    pz[j] = base[p * 6 + 2];
    mir[p] = make_float4(px[j], py[j], pz[j], 0.0f);
  }
  if (tid < 4) kslot[tid] = 0ull;
  if (tid == 0) sel[0] = 0;
  __syncthreads();

  float4 c0 = mir[0];
  float cx = c0.x, cy = c0.y, cz = c0.z;

#pragma unroll
  for (int j = 0; j < 8; ++j) {
    const float dx = __fsub_rn(px[j], cx);
    const float dy = __fsub_rn(py[j], cy);
    const float dz = __fsub_rn(pz[j], cz);
    dv[j] = __fadd_rn(
        __fadd_rn(__fmul_rn(dx, dx), __fmul_rn(dy, dy)), __fmul_rn(dz, dz));
  }

  for (int it = 1; it < NG; ++it) {
    // f32 max tree (fmax returns an input bit-exactly; dv >= 0, no NaN)
    float t[4];
#pragma unroll
    for (int j = 0; j < 4; ++j) t[j] = fmaxf(dv[j], dv[j + 4]);
    t[0] = fmaxf(t[0], t[2]);
    t[1] = fmaxf(t[1], t[3]);
    const float m = fmaxf(t[0], t[1]);
    // first j with dv[j]==m (descending loop -> smallest j wins = min p)
    int jj = 0;
#pragma unroll
    for (int j = 7; j >= 0; --j)
      if (dv[j] == m) jj = j;
    const unsigned lo = (unsigned)(NP - 1 - tid - (jj << 10));  // 8191 - p

    // wave max of m's bits (dv>=0: u32 order == f32 order)
    const unsigned sv = __float_as_uint(m);
    unsigned r = sv;
    DPP_MAX_U32(r, 0x111); DPP_MAX_U32(r, 0x112); DPP_MAX_U32(r, 0x114);
    DPP_MAX_U32(r, 0x118); DPP_MAX_U32(r, 0x142); DPP_MAX_U32(r, 0x143);
    const unsigned smax = (unsigned)__builtin_amdgcn_readlane((int)r, 63);

    const unsigned long long mk = __ballot(sv == smax);
    unsigned wlo;
    if (mk & (mk - 1)) {          // value tie across lanes: max lo = min p
      unsigned long long mm = mk; unsigned best = 0;
      while (mm) {
        const int l = __builtin_ctzll(mm);
        const unsigned c = (unsigned)__builtin_amdgcn_readlane((int)lo, l);
        if (c > best) best = c;
        mm &= mm - 1;
      }
      wlo = best;
    } else {
      wlo = (unsigned)__builtin_amdgcn_readlane((int)lo, __builtin_ctzll(mk));
    }

    // 16 non-returning LDS atomics to one address (serialize in LDS unit,
    // latency hidden before the barrier's lgkmcnt drain).
    const int sl = it & 3;
    if (lane == 0)
      atomicMax(&kslot[sl],
                ((unsigned long long)smax << 32) | wlo);
    if (tid == 0) kslot[(it + 2) & 3] = 0ull;   // prep slot for iter it+2
    __syncthreads();

    // post-barrier chain: ONE broadcast b64 read -> gi -> ONE b128 read.
    const unsigned long long g = kslot[sl];
    const int gi = (NP - 1) - (int)(unsigned)(g & 0xFFFFFFFFu);
    if (tid == 0) sel[it] = gi;

    const float4 c = mir[gi];     // one ds_read_b128 broadcast
    cx = c.x; cy = c.y; cz = c.z;

#pragma unroll
    for (int j = 0; j < 8; ++j) {
      const float dx = __fsub_rn(px[j], cx);
      const float dy = __fsub_rn(py[j], cy);
      const float dz = __fsub_rn(pz[j], cz);
      const float d = __fadd_rn(
          __fadd_rn(__fmul_rn(dx, dx), __fmul_rn(dy, dy)), __fmul_rn(dz, dz));
      dv[j] = fminf(dv[j], d);
    }
  }
  __syncthreads();

  if (tid < NG) {
    const int g = tid;
    const int p = sel[g];
    const float4 c = mir[p];
    const size_t cb = (size_t)(b * NG + g) * 3;
    out[CENTER_OFF + cb + 0] = c.x;
    out[CENTER_OFF + cb + 1] = c.y;
    out[CENTER_OFF + cb + 2] = c.z;
    cidx[b * NG + g] = p;
  }
}

// ---------------------------------------------------------------------------
// Kernel 2: 32-NN, R12 structure: TWO-LEVEL histogram select + tiny-pool
// extraction. R27: float2-vectorized point loads (bit-exact values).
// L1: 2048 bins of fv>>21 -> bin B1 + run1. L2: re-histogram bin-B1 keys
// on (fv>>10)&0x7FF -> B2 + run2. Winners: run1+run2 <= 31; candidates
// cap 224. Wave 0 extracts the 32 smallest u64 keys (DPP+ballot).
// ---------------------------------------------------------------------------
__global__ __launch_bounds__(256) void knn_kernel(
    const float* __restrict__ xyz, float* __restrict__ out,
    const int* __restrict__ cidx)
{
  __shared__ unsigned bins[2048];
  __shared__ unsigned part[256];
  __shared__ int sB, sRun;
  __shared__ unsigned wcnt, ccnt;
  __shared__ unsigned long long wbuf[32];
  __shared__ unsigned long long cbuf[224];
  __shared__ int widx[GS];

  const int bg = blockIdx.x;
  const int b = bg >> 9;
  const int tid = threadIdx.x;
  const int lane = tid & 63;
  const int wave = tid >> 6;
  const float* base = xyz + (size_t)b * NP * NC;

  const int pc = cidx[bg] & (NP - 1);  // clamp: fault-proof under any state
  const float cx = base[pc * 6 + 0];
  const float cy = base[pc * 6 + 1];
  const float cz = base[pc * 6 + 2];
  const float cc = __fadd_rn(
      __fadd_rn(__fmul_rn(cx, cx), __fmul_rn(cy, cy)), __fmul_rn(cz, cz));

  for (int i = tid; i < 2048; i += 256) bins[i] = 0;
  if (tid == 0) { wcnt = 0; ccnt = 0; }
  __syncthreads();

  unsigned fv[32];
#pragma unroll
  for (int j = 0; j < 32; ++j) {
    const int p = tid + (j << 8);
    const float2 xy = *reinterpret_cast<const float2*>(base + p * 6);
    const float x = xy.x;
    const float y = xy.y;
    const float z = base[p * 6 + 2];
    const float xx = __fadd_rn(
        __fadd_rn(__fmul_rn(x, x), __fmul_rn(y, y)), __fmul_rn(z, z));
    const float dot = __fadd_rn(
        __fadd_rn(__fmul_rn(cx, x), __fmul_rn(cy, y)), __fmul_rn(cz, z));
    const float d2 = __fsub_rn(__fadd_rn(cc, xx), __fmul_rn(2.0f, dot));
    unsigned u = __float_as_uint(d2);
    u ^= ((unsigned)((int)u >> 31)) | 0x80000000u;  // sortable (d2 can be <0)
    fv[j] = u;
    atomicAdd(&bins[u >> 21], 1u);
  }
  __syncthreads();

  // ---- Level 1: bin containing rank 32 ----
  {
    unsigned s = 0;
#pragma unroll
    for (int i = 0; i < 8; ++i) s += bins[tid * 8 + i];
    part[tid] = s;
  }
  __syncthreads();
  if (wave == 0) {
    const unsigned q = part[4 * lane + 0] + part[4 * lane + 1] +
                       part[4 * lane + 2] + part[4 * lane + 3];
    unsigned cum = q;
#pragma unroll
    for (int off = 1; off < 64; off <<= 1) {
      const unsigned t = __shfl_up(cum, (unsigned)off);
      if (lane >= off) cum += t;
    }
    const unsigned long long mb = __ballot(cum >= 32u);
    const int ls = __builtin_ctzll(mb);
    unsigned run = (unsigned)__builtin_amdgcn_readlane((int)cum, ls) -
                   (unsigned)__builtin_amdgcn_readlane((int)q, ls);
    unsigned h[32];
#pragma unroll
    for (int i = 0; i < 32; ++i) h[i] = bins[(ls << 5) + i];  // broadcast
    int T = ls << 5;
#pragma unroll
    for (int i = 0; i < 32; ++i) {
      if (run + h[i] >= 32u) { T = (ls << 5) + i; break; }
      run += h[i];
    }
    if (lane == 0) { sB = T; sRun = (int)run; }
  }
  __syncthreads();
  const int B1 = sB;
  const unsigned run1 = (unsigned)sRun;
  const unsigned r2 = 32u - run1;              // rank within bin B1, in [1,32]
  __syncthreads();

  // ---- Level 2: refine within bin B1 on bits 20..10 ----
  for (int i = tid; i < 2048; i += 256) bins[i] = 0;
  __syncthreads();
#pragma unroll
  for (int j = 0; j < 32; ++j)
    if ((int)(fv[j] >> 21) == B1) atomicAdd(&bins[(fv[j] >> 10) & 0x7FF], 1u);
  __syncthreads();
  {
    unsigned s = 0;
#pragma unroll
    for (int i = 0; i < 8; ++i) s += bins[tid * 8 + i];
    part[tid] = s;
  }
  __syncthreads();
  if (wave == 0) {
    const unsigned q = part[4 * lane + 0] + part[4 * lane + 1] +
                       part[4 * lane + 2] + part[4 * lane + 3];
    unsigned cum = q;
#pragma unroll
    for (int off = 1; off < 64; off <<= 1) {
      const unsigned t = __shfl_up(cum, (unsigned)off);
      if (lane >= off) cum += t;
    }
    const unsigned long long mb = __ballot(cum >= r2);  // total >= r2 always
    const int ls = __builtin_ctzll(mb);
    unsigned run = (unsigned)__builtin_amdgcn_readlane((int)cum, ls) -
                   (unsigned)__builtin_amdgcn_readlane((int)q, ls);
    unsigned h[32];
#pragma unroll
    for (int i = 0; i < 32; ++i) h[i] = bins[(ls << 5) + i];
    int T = ls << 5;
#pragma unroll
    for (int i = 0; i < 32; ++i) {
      if (run + h[i] >= r2) { T = (ls << 5) + i; break; }
      run += h[i];
    }
    if (lane == 0) { sB = T; sRun = (int)run; }
  }
  __syncthreads();
  const int B2 = sB;                            // run1 + sRun <= 31 winners
  const unsigned key22 = ((unsigned)B1 << 11) | (unsigned)B2;

  // ---- compaction ----
#pragma unroll
  for (int j = 0; j < 32; ++j) {
    const unsigned hi11 = fv[j] >> 21;
    const unsigned top22 = fv[j] >> 10;
    if (top22 <= key22) {
      const unsigned long long key =
          ((unsigned long long)fv[j] << 32) | (unsigned)(tid + (j << 8));
      if (top22 < key22) {
        if ((int)hi11 < B1 || hi11 == (unsigned)B1) {  // always true; winners
          const unsigned pos = atomicAdd(&wcnt, 1u);
          if (pos < 32u) wbuf[pos] = key;
        }
      } else {
        const unsigned pos = atomicAdd(&ccnt, 1u);
        if (pos < 224u) cbuf[pos] = key;
      }
    }
  }
  __syncthreads();

  // ---- wave 0: extract 32 smallest u64 keys from the pool ----
  if (wave == 0) {
    const int W = (int)(wcnt < 32u ? wcnt : 32u);     // provably <= 31
    const int C = (int)(ccnt < 224u ? ccnt : 224u);
    unsigned long long pool[4];
#pragma unroll
    for (int rr = 0; rr < 4; ++rr) {
      const int i = lane + (rr << 6);
      unsigned long long k = ~0ull;
      if (i < W) k = wbuf[i];
      else if (i - W < C) k = cbuf[i - W];
      pool[rr] = k;
    }
    unsigned long long l0 = pool[0] < pool[1] ? pool[0] : pool[1];
    unsigned long long l1 = pool[2] < pool[3] ? pool[2] : pool[3];
    unsigned long long loc = l0 < l1 ? l0 : l1;

    unsigned long long mykey = 0;
    for (int k = 0; k < GS; ++k) {
      const unsigned hi = (unsigned)(loc >> 32);
      unsigned r = hi;
      DPP_MIN_U32(r, 0x111); DPP_MIN_U32(r, 0x112); DPP_MIN_U32(r, 0x114);
      DPP_MIN_U32(r, 0x118); DPP_MIN_U32(r, 0x142); DPP_MIN_U32(r, 0x143);
      const unsigned minhi = (unsigned)__builtin_amdgcn_readlane((int)r, 63);

      const unsigned long long m = __ballot(hi == minhi);
      unsigned lo;
      if (m & (m - 1)) {                       // value tie: min low word
        unsigned long long mm = m; unsigned best = 0xFFFFFFFFu;
        while (mm) {
          const int l = __builtin_ctzll(mm);
          const unsigned c =
              (unsigned)__builtin_amdgcn_readlane((int)(unsigned)loc, l);
          if (c < best) best = c;
          mm &= mm - 1;
        }
        lo = best;
      } else {
        lo = (unsigned)__builtin_amdgcn_readlane((int)(unsigned)loc,
                                                 __builtin_ctzll(m));
      }
      const unsigned long long win = ((unsigned long long)minhi << 32) | lo;
      if (lane == k) mykey = win;
      if (loc == win) {                        // unique owner (keys unique)
#pragma unroll
        for (int rr = 0; rr < 4; ++rr)
          if (pool[rr] == win) pool[rr] = ~0ull;
        l0 = pool[0] < pool[1] ? pool[0] : pool[1];
        l1 = pool[2] < pool[3] ? pool[2] : pool[3];
        loc = l0 < l1 ? l0 : l1;
      }
    }
    if (lane < GS) widx[lane] = (int)(unsigned)(mykey & 0xFFFFFFFFu);
  }
  __syncthreads();

  if (tid < GS) {
    const int p = widx[tid] & (NP - 1);  // in-bounds by construction
    const float v0 = base[p * 6 + 0];
    const float v1 = base[p * 6 + 1];
    const float v2 = base[p * 6 + 2];
    const size_t ob = ((size_t)bg * GS + tid) * 6;
    out[ob + 0] = __fsub_rn(v0, cx);
    out[ob + 1] = __fsub_rn(v1, cy);
    out[ob + 2] = __fsub_rn(v2, cz);
    out[ob + 3] = base[p * 6 + 3];  // extras: raw f32 passthrough
    out[ob + 4] = base[p * 6 + 4];
    out[ob + 5] = base[p * 6 + 5];
    out[IDX_OFF + (size_t)bg * GS + tid] = (float)p;  // idx as f32 value
  }
}

extern "C" void kernel_launch(void* const* d_in, const int* in_sizes, int n_in,
                              void* d_out, int out_size, void* d_ws,
                              size_t ws_size, hipStream_t stream)
{
  const float* xyz = (const float*)d_in[0];
  float* out = (float*)d_out;
  int* cidx = (int*)d_ws;  // NB*NG ints = 16 KiB scratch

  hipLaunchKernelGGL(fps_kernel, dim3(NB), dim3(1024), 0, stream,
                     xyz, out, cidx);
  hipLaunchKernelGGL(knn_kernel, dim3(NB * NG), dim3(256), 0, stream,
                     xyz, out, cidx);
}